// Round 2
// baseline (230.472 us; speedup 1.0000x reference)
//
#include <hip/hip_runtime.h>
#include <math.h>

// PCEN: x[B=64, C=128, T=4000] fp32.
// smooth[0]=x[0]; smooth[t]=(1-s)*smooth[t-1]+s*x[t], s=0.025
// out = sqrt(x/(smooth+1e-6)^0.98 + 2) - sqrt(2)
//
// R2 change: TWO channels per block, fully interleaved. R1 showed the kernel
// is latency/phase-convoy bound (VALUBusy 21%, HBM 31%, dur unchanged when
// VALU work was cut by a third): each wave had only 4 loads in flight and all
// waves stall on the same dependent scan/barrier phases. Doubling the
// independent streams per wave doubles MLP (8 float4 loads outstanding) and
// ILP in every dependent chain (shuffle scan, A256 compose chain, epilogue),
// and halves barriers per byte. Math is unchanged from R1:
//   - chunk coefficient is the literal (1-s)^4 (tail padded with x=0, causal),
//   - B-only shuffle scan with literal per-step coefficients,
//   - cross-wave prefix via literal (1-s)^256 straight-line chain,
//   - per-lane exclusive coefficient from one v_exp_f32.

constexpr int   TLEN = 4000;
constexpr int   NF4  = 1000;   // float4s per channel
constexpr int   NTH  = 256;
constexpr int   CPB  = 2;      // channels per block
constexpr float S_C  = 0.025f;
constexpr float A_1  = 1.0f - S_C;

constexpr float fpow(float b, int n) {
    float r = 1.0f;
    for (int i = 0; i < n; ++i) r *= b;
    return r;
}
constexpr float A_2  = fpow(A_1, 2);
constexpr float A_3  = fpow(A_1, 3);
constexpr float A256 = fpow(A_1, 256);   // one full wave-segment (64 chunks * 4)

// 4*log2(1-s): per-lane exclusive coefficient is exp2(lane * L2A4)
constexpr float L2A4 = -0.14610359f;

constexpr float ALPHA = 0.98f;
constexpr float EPS_C = 1e-6f;
constexpr float SQRT2 = 1.41421356237309515f;

__device__ __forceinline__ float pcen_elem(float x, float sm) {
    float t = sm + EPS_C;
    float p = __builtin_amdgcn_exp2f(-ALPHA * __builtin_amdgcn_logf(t)); // t^-alpha
    float y = fmaf(x, p, 2.0f);
    return __builtin_amdgcn_sqrtf(y) - SQRT2;
}

__global__ __launch_bounds__(NTH) void pcen_kernel(const float* __restrict__ x,
                                                   float* __restrict__ out,
                                                   int nch) {
    const int    tid  = threadIdx.x;
    const int    lane = tid & 63;
    const int    wv   = tid >> 6;
    const int    ch0  = blockIdx.x * CPB;
    const bool   has1 = (ch0 + 1 < nch);
    const size_t base = (size_t)ch0 * TLEN;

    const float4* __restrict__ x4 = (const float4*)(x + base);
    float4*       __restrict__ o4 = (float4*)(out + base);

    // ---- coalesced loads: 8 lane-dense float4 loads in flight ----
    float4 v[CPB][4];
    bool   act[4];
#pragma unroll
    for (int k = 0; k < 4; ++k) {
        int f4 = tid + NTH * k;
        act[k]  = (f4 < NF4);
        v[0][k] = act[k]           ? x4[f4]       : make_float4(0.f, 0.f, 0.f, 0.f);
        v[1][k] = (act[k] && has1) ? x4[NF4 + f4] : make_float4(0.f, 0.f, 0.f, 0.f);
    }

    // ---- per-mini-chunk offset B (coefficient is uniformly A_1^4) ----
    // B = A_1^3*b0 + s*(A_1^2*x1 + A_1*x2 + x3);  b0 = s*x0 (or x0 at t=0)
    float B[CPB][4];
#pragma unroll
    for (int c = 0; c < CPB; ++c) {
#pragma unroll
        for (int k = 0; k < 4; ++k) {
            float4 r  = v[c][k];
            float  b0 = (tid == 0 && k == 0) ? r.x : S_C * r.x;  // smooth[0]=x[0]
            B[c][k] = fmaf(A_3, b0, S_C * fmaf(A_2, r.y, fmaf(A_1, r.z, r.w)));
        }
    }

    // ---- 8 interleaved inclusive wave scans over B only ----
    constexpr float CD[6] = { fpow(A_1, 4),  fpow(A_1, 8),  fpow(A_1, 16),
                              fpow(A_1, 32), fpow(A_1, 64), fpow(A_1, 128) };
#pragma unroll
    for (int s = 0; s < 6; ++s) {
        const int   d = 1 << s;
        const float cc = CD[s];
        float Bp[CPB][4];
#pragma unroll
        for (int c = 0; c < CPB; ++c)
#pragma unroll
            for (int k = 0; k < 4; ++k) Bp[c][k] = __shfl_up(B[c][k], d);
        const bool ok = (lane >= d);
#pragma unroll
        for (int c = 0; c < CPB; ++c)
#pragma unroll
            for (int k = 0; k < 4; ++k)
                B[c][k] = fmaf(cc, ok ? Bp[c][k] : 0.0f, B[c][k]);
    }

    // ---- wave totals -> LDS (per channel: 16 B values, m = 4*seg + wave) ----
    __shared__ float sB[CPB][16];
    if (lane == 63) {
#pragma unroll
        for (int c = 0; c < CPB; ++c)
#pragma unroll
            for (int k = 0; k < 4; ++k) sB[c][4 * k + wv] = B[c][k];
    }
    __syncthreads();

    // ---- entering prefix per (wave, segment): chain with literal A256 ----
    // E[c][k] composes wave totals m < 4k+wv; wave-uniform straight-line.
    float E[CPB][4];
    {
        float e0 = 0.0f, e1 = 0.0f;
#define CH(m)  do { e0 = fmaf(A256, e0, sB[0][m]); e1 = fmaf(A256, e1, sB[1][m]); } while (0)
#define CAP(k) do { E[0][k] = e0; E[1][k] = e1; } while (0)
        if (wv == 0) {
            CAP(0);
            CH(0); CH(1); CH(2); CH(3);     CAP(1);
            CH(4); CH(5); CH(6); CH(7);     CAP(2);
            CH(8); CH(9); CH(10); CH(11);   CAP(3);
        } else if (wv == 1) {
            CH(0);                          CAP(0);
            CH(1); CH(2); CH(3); CH(4);     CAP(1);
            CH(5); CH(6); CH(7); CH(8);     CAP(2);
            CH(9); CH(10); CH(11); CH(12);  CAP(3);
        } else if (wv == 2) {
            CH(0); CH(1);                   CAP(0);
            CH(2); CH(3); CH(4); CH(5);     CAP(1);
            CH(6); CH(7); CH(8); CH(9);     CAP(2);
            CH(10); CH(11); CH(12); CH(13); CAP(3);
        } else {
            CH(0); CH(1); CH(2);            CAP(0);
            CH(3); CH(4); CH(5); CH(6);     CAP(1);
            CH(7); CH(8); CH(9); CH(10);    CAP(2);
            CH(11); CH(12); CH(13); CH(14); CAP(3);
        }
#undef CH
#undef CAP
    }

    // ---- per-lane exclusive coefficient A_1^(4*lane) via one v_exp_f32 ----
    const float Al = __builtin_amdgcn_exp2f((float)lane * L2A4);

    // ---- exclusive prefix, replay, epilogue, dense stores (2 ch interleaved) ----
#pragma unroll
    for (int k = 0; k < 4; ++k) {
#pragma unroll
        for (int c = 0; c < CPB; ++c) {
            float Bi = __shfl_up(B[c][k], 1);
            if (lane == 0) Bi = 0.0f;
            float sm = fmaf(Al, E[c][k], Bi);    // smoothed value entering chunk

            float4 r  = v[c][k];
            float  b0 = (tid == 0 && k == 0) ? r.x : S_C * r.x;
            float  s0 = fmaf(A_1, sm, b0);
            float  s1 = fmaf(A_1, s0, S_C * r.y);
            float  s2 = fmaf(A_1, s1, S_C * r.z);
            float  s3 = fmaf(A_1, s2, S_C * r.w);

            float4 o;
            o.x = pcen_elem(r.x, s0);
            o.y = pcen_elem(r.y, s1);
            o.z = pcen_elem(r.z, s2);
            o.w = pcen_elem(r.w, s3);

            int f4 = tid + NTH * k;
            if (act[k] && (c == 0 || has1)) o4[c * NF4 + f4] = o;
        }
    }
}

extern "C" void kernel_launch(void* const* d_in, const int* in_sizes, int n_in,
                              void* d_out, int out_size, void* d_ws, size_t ws_size,
                              hipStream_t stream) {
    const float* x   = (const float*)d_in[0];
    float*       out = (float*)d_out;
    const int nch    = in_sizes[0] / TLEN;            // 8192 channels
    const int grid   = (nch + CPB - 1) / CPB;         // 4096 blocks
    pcen_kernel<<<grid, NTH, 0, stream>>>(x, out, nch);
}

// Round 3
// 228.349 us; speedup vs baseline: 1.0093x; 1.0093x over previous
//
#include <hip/hip_runtime.h>
#include <math.h>

// PCEN: x[B=64, C=128, T=4000] fp32.
// smooth[0]=x[0]; smooth[t]=(1-s)*smooth[t-1]+s*x[t], s=0.025
// out = sqrt(x/(smooth+1e-6)^0.98 + 2) - sqrt(2)
//
// R3: ONE WAVE PER CHANNEL — no LDS, no __syncthreads, no cross-wave anything.
// R1/R2 showed a latency-convoy profile (all pipes <35% busy, wave lifetime
// ~16us vs ~1.2us critical path): hipcc drains vmcnt(0)+lgkmcnt(0) before
// every s_barrier, so the old 4-wave-per-channel block phase-locked the whole
// device. Here lane l owns float4 chunks {l + 64k, k=0..15} (lane-dense,
// coalesced); the channel scan is done entirely with wave shuffles:
//   - B-only shuffle scan, 6 steps, literal coefficients (1-s)^(4d),
//   - segment totals via __shfl(B[k],63) (wave-uniform), composed with the
//     literal (1-s)^256 in a 15-FMA chain interleaved into the epilogue,
//   - per-lane exclusive coefficient (1-s)^(4*lane) from one v_exp_f32.
// Waves are fully independent -> they desynchronize and cover each other's
// HBM stalls; no waitcnt-drain points exist.

constexpr int   TLEN = 4000;
constexpr int   NF4  = 1000;   // float4 chunks per channel
constexpr int   NTH  = 256;    // 4 independent waves = 4 channels per block
constexpr int   KPL  = 16;     // chunks per lane (64*16 = 1024 >= 1000)
constexpr float S_C  = 0.025f;
constexpr float A_1  = 1.0f - S_C;

constexpr float fpow(float b, int n) {
    float r = 1.0f;
    for (int i = 0; i < n; ++i) r *= b;
    return r;
}
constexpr float A_2  = fpow(A_1, 2);
constexpr float A_3  = fpow(A_1, 3);
constexpr float A256 = fpow(A_1, 256);   // one segment = 64 lanes * 4 elems

// 4*log2(1-s): per-lane exclusive coefficient is exp2(lane * L2A4)
constexpr float L2A4 = -0.14610359f;

constexpr float ALPHA = 0.98f;
constexpr float EPS_C = 1e-6f;
constexpr float SQRT2 = 1.41421356237309515f;

__device__ __forceinline__ float pcen_elem(float x, float sm) {
    float t = sm + EPS_C;
    float p = __builtin_amdgcn_exp2f(-ALPHA * __builtin_amdgcn_logf(t)); // t^-alpha
    float y = fmaf(x, p, 2.0f);
    return __builtin_amdgcn_sqrtf(y) - SQRT2;
}

__global__ __launch_bounds__(NTH) void pcen_kernel(const float* __restrict__ x,
                                                   float* __restrict__ out,
                                                   int nch) {
    const int lane = threadIdx.x & 63;
    const int ch   = blockIdx.x * (NTH / 64) + (threadIdx.x >> 6);
    if (ch >= nch) return;

    const size_t base = (size_t)ch * TLEN;
    const float4* __restrict__ x4 = (const float4*)(x + base);
    float4*       __restrict__ o4 = (float4*)(out + base);

    // ---- coalesced load: 16 lane-dense float4 loads, all in flight ----
    float4 v[KPL];
#pragma unroll
    for (int k = 0; k < KPL; ++k) {
        int f4 = lane + 64 * k;
        v[k] = (f4 < NF4) ? x4[f4] : make_float4(0.f, 0.f, 0.f, 0.f);
    }

    // ---- per-chunk offset B (coefficient is uniformly A_1^4) ----
    // B = A_1^3*b0 + s*(A_1^2*x1 + A_1*x2 + x3);  b0 = s*x0 (or x0 at t=0)
    float B[KPL];
#pragma unroll
    for (int k = 0; k < KPL; ++k) {
        float4 r  = v[k];
        float  b0 = (lane == 0 && k == 0) ? r.x : S_C * r.x;  // smooth[0]=x[0]
        B[k] = fmaf(A_3, b0, S_C * fmaf(A_2, r.y, fmaf(A_1, r.z, r.w)));
    }

    // ---- 16 interleaved inclusive wave scans over B (6 shuffle steps) ----
    constexpr float CD[6] = { fpow(A_1, 4),  fpow(A_1, 8),  fpow(A_1, 16),
                              fpow(A_1, 32), fpow(A_1, 64), fpow(A_1, 128) };
#pragma unroll
    for (int s = 0; s < 6; ++s) {
        const int   d  = 1 << s;
        const float cc = CD[s];
        float Bp[KPL];
#pragma unroll
        for (int k = 0; k < KPL; ++k) Bp[k] = __shfl_up(B[k], d);
        const bool ok = (lane >= d);
#pragma unroll
        for (int k = 0; k < KPL; ++k)
            B[k] = fmaf(cc, ok ? Bp[k] : 0.0f, B[k]);
    }

    // ---- per-lane exclusive coefficient A_1^(4*lane) via one v_exp_f32 ----
    const float Al = __builtin_amdgcn_exp2f((float)lane * L2A4);

    // ---- epilogue: per segment k, entering value e (wave-uniform chain),
    //      exclusive shuffle, replay, pcen, dense store ----
    float e = 0.0f;   // smoothed value entering segment k (uniform across lanes)
#pragma unroll
    for (int k = 0; k < KPL; ++k) {
        float Tk = (k < KPL - 1) ? __shfl(B[k], 63) : 0.0f;  // segment total
        float Bi = __shfl_up(B[k], 1);
        if (lane == 0) Bi = 0.0f;
        float sm = fmaf(Al, e, Bi);          // smoothed value entering chunk

        float4 r  = v[k];
        float  b0 = (lane == 0 && k == 0) ? r.x : S_C * r.x;
        float  s0 = fmaf(A_1, sm, b0);
        float  s1 = fmaf(A_1, s0, S_C * r.y);
        float  s2 = fmaf(A_1, s1, S_C * r.z);
        float  s3 = fmaf(A_1, s2, S_C * r.w);

        float4 o;
        o.x = pcen_elem(r.x, s0);
        o.y = pcen_elem(r.y, s1);
        o.z = pcen_elem(r.z, s2);
        o.w = pcen_elem(r.w, s3);

        int f4 = lane + 64 * k;
        if (f4 < NF4) o4[f4] = o;

        e = fmaf(A256, e, Tk);               // advance to next segment
    }
}

extern "C" void kernel_launch(void* const* d_in, const int* in_sizes, int n_in,
                              void* d_out, int out_size, void* d_ws, size_t ws_size,
                              hipStream_t stream) {
    const float* x   = (const float*)d_in[0];
    float*       out = (float*)d_out;
    const int nch    = in_sizes[0] / TLEN;               // 8192 channels
    const int wpb    = NTH / 64;                         // 4 channels per block
    const int grid   = (nch + wpb - 1) / wpb;            // 2048 blocks
    pcen_kernel<<<grid, NTH, 0, stream>>>(x, out, nch);
}